// Round 1
// baseline (824.100 us; speedup 1.0000x reference)
//
#include <hip/hip_runtime.h>

// Sylo forward: out[n,o,h,w] = rs[n,o,h] + cs[n,o,w] - P[n,o,h,w] + bias[o], diag=0
//   T[o,c] = L[o,c] @ L[o,c]^T (rank-4)
//   P = sum_c X[n,c] .* T[o,c]
//   rs[n,o,h] = sum_{c,r} L[o,c,h,r] * (X[n,c] @ L[o,c])[h,r]
//   cs[n,o,w] = sum_{c,r} L[o,c,w,r] * (X[n,c]^T @ L[o,c])[w,r]
//
// N=8, C_IN=4, C_OUT=64, DIM=512, RANK=4

#define DIMS 512
#define CIN 4
#define COUT 64
#define NB 8
#define RANKS 4

typedef float f32x4 __attribute__((ext_vector_type(4)));  // nontemporal-store-able

// ws layout (floats):
//   Lpk  [CIN][DIM][COUT*RANK]   = 4*512*256 = 524288   (2 MiB)
//   rs   [NB][COUT][DIM]         = 262144               (1 MiB)
//   cs   [NB][COUT][DIM]         = 262144               (1 MiB)
#define LPK_ELEMS (CIN * DIMS * COUT * RANKS)
#define SUMS_ELEMS (NB * COUT * DIMS)

// ---------------------------------------------------------------------------
// Kernel 0: pack L[o][c][k][r] -> Lpk[c][k][o*4+r]  (coalesced writes)
// ---------------------------------------------------------------------------
__global__ __launch_bounds__(256) void pack_L(const float* __restrict__ L,
                                              float* __restrict__ Lpk) {
    int idx = blockIdx.x * 256 + threadIdx.x;   // 524288 total
    int oc = idx & 255;
    int k  = (idx >> 8) & 511;
    int c  = idx >> 17;
    int o = oc >> 2, r = oc & 3;
    Lpk[idx] = L[((o * CIN + c) * DIMS + k) * RANKS + r];
}

// ---------------------------------------------------------------------------
// Kernel 1: rs (mode 0) and cs (mode 1).
// v2: 512-thread blocks (8 waves) -> 16 waves/CU (was 8).  Each thread owns
// 2 d-rows x 4 oc (one o's 4 ranks); grid unchanged (512 blocks).
// ---------------------------------------------------------------------------
#define XPAD 68   // 16B-aligned float4 rows, 2-way-max LDS bank aliasing

__global__ __launch_bounds__(512, 4) void sums_kernel(const float* __restrict__ X,
                                                      const float* __restrict__ Lpk,
                                                      float* __restrict__ sums) {
    const int mode = blockIdx.y;                 // 0: rs, 1: cs
    const int n    = blockIdx.x >> 5;            // 8
    const int d0   = (blockIdx.x & 31) << 4;     // 32 tiles of 16 rows
    const int t    = threadIdx.x;
    const int lane = t & 63;                     // -> oc0 = 4*lane (o = lane)
    const int drow = (t >> 6) << 1;              // 0,2,...,14 per wave

    __shared__ float Xsm[16 * XPAD];
    const float4* __restrict__ Lpk4 = (const float4*)Lpk;

    float rsacc[2] = {0.f, 0.f};

    for (int c = 0; c < CIN; ++c) {
        float acc[2][4];
#pragma unroll
        for (int i = 0; i < 2; ++i)
#pragma unroll
            for (int j = 0; j < 4; ++j) acc[i][j] = 0.f;

        const float* __restrict__ Xc = X + (size_t)(n * CIN + c) * DIMS * DIMS;

        for (int k0 = 0; k0 < DIMS; k0 += 64) {
            __syncthreads();  // protect previous tile's reads
            if (mode == 0) {
                // Xsm[dd][kk] = X[n][c][d0+dd][k0+kk]  (coalesced 64-wide)
                int kk = t & 63, dd = t >> 6;          // dd 0..7
#pragma unroll
                for (int j = 0; j < 2; ++j)
                    Xsm[(dd + 8 * j) * XPAD + kk] = Xc[(d0 + dd + 8 * j) * DIMS + k0 + kk];
            } else {
                // Xsm[dd][kk] = X[n][c][k0+kk][d0+dd]  (16-wide segments)
                int dd = t & 15, kk0 = t >> 4;         // kk0 0..31
#pragma unroll
                for (int j = 0; j < 2; ++j)
                    Xsm[dd * XPAD + kk0 + 32 * j] = Xc[(k0 + kk0 + 32 * j) * DIMS + d0 + dd];
            }
            __syncthreads();

#pragma unroll 2
            for (int k = 0; k < 64; k += 4) {
                float4 lv0 = Lpk4[(c * DIMS + k0 + k + 0) * 64 + lane];
                float4 lv1 = Lpk4[(c * DIMS + k0 + k + 1) * 64 + lane];
                float4 lv2 = Lpk4[(c * DIMS + k0 + k + 2) * 64 + lane];
                float4 lv3 = Lpk4[(c * DIMS + k0 + k + 3) * 64 + lane];
#pragma unroll
                for (int i = 0; i < 2; ++i) {
                    float4 xv = *(const float4*)&Xsm[(drow + i) * XPAD + k];
                    acc[i][0] += xv.x * lv0.x + xv.y * lv1.x + xv.z * lv2.x + xv.w * lv3.x;
                    acc[i][1] += xv.x * lv0.y + xv.y * lv1.y + xv.z * lv2.y + xv.w * lv3.y;
                    acc[i][2] += xv.x * lv0.z + xv.y * lv1.z + xv.z * lv2.z + xv.w * lv3.z;
                    acc[i][3] += xv.x * lv0.w + xv.y * lv1.w + xv.z * lv2.w + xv.w * lv3.w;
                }
            }
        }
        // epilogue: fold L[o,c,row,r] and reduce over this thread's 4 ranks
#pragma unroll
        for (int i = 0; i < 2; ++i) {
            float4 lf = Lpk4[(c * DIMS + d0 + drow + i) * 64 + lane];
            rsacc[i] += lf.x * acc[i][0] + lf.y * acc[i][1] + lf.z * acc[i][2] + lf.w * acc[i][3];
        }
    }

    float* __restrict__ dst = sums + mode * SUMS_ELEMS;
#pragma unroll
    for (int i = 0; i < 2; ++i)
        dst[(n * COUT + lane) * DIMS + d0 + drow + i] = rsacc[i];
}

// ---------------------------------------------------------------------------
// Kernel 2 (v2): out[n,o,h,w] = rs + cs - P + bias, zero diagonal.
// Block: 2 consecutive o  x  32x32 (h,w) tile; 256 threads; thread owns one
// float4 row-segment per (n,o).  T slice lives in REGISTERS (2o x 4c x 4w =
// 32 regs); LDS only holds the small L fragments (8 KB) -> 4-5 blocks/CU.
// Each X float4 load feeds both o's -> X L2 traffic halved vs 1-o/64x64.
// Grid x = o-pair (fastest) so consecutive blocks share X tiles in L2.
// ---------------------------------------------------------------------------
#define OPB 2

__global__ __launch_bounds__(256, 4) void final_kernel(const float* __restrict__ X,
                                                       const float* __restrict__ L,
                                                       const float* __restrict__ bias,
                                                       const float* __restrict__ sums,
                                                       float* __restrict__ out) {
    const int o0   = blockIdx.x * OPB;     // 32 o-pairs
    const int tile = blockIdx.y;           // 256 tiles of 32x32
    const int h0   = (tile & 15) << 5;
    const int w0   = (tile >> 4) << 5;
    const int t    = threadIdx.x;
    const int ww4  = t & 7;                // float4 column within tile
    const int hh   = t >> 3;               // row 0..31

    // L fragments, rank-contiguous (one float4 per (o2,c,d))
    __shared__ float Lhs[OPB * CIN * 32 * RANKS];   // 4 KB
    __shared__ float Lws[OPB * CIN * 32 * RANKS];   // 4 KB

    {
        const float4* __restrict__ L4 = (const float4*)L;
        float4* __restrict__ LhsV = (float4*)Lhs;
        float4* __restrict__ LwsV = (float4*)Lws;
        for (int idx = t; idx < 2 * OPB * CIN * 32; idx += 256) {   // 512
            int side = idx >> 8;           // 0: h-side, 1: w-side
            int rem  = idx & 255;          // o2*128 + c*32 + d
            int o2   = rem >> 7;
            int c    = (rem >> 5) & 3;
            int d    = rem & 31;
            int base = side ? w0 : h0;
            float4 v = L4[((o0 + o2) * CIN + c) * DIMS + base + d];
            (side ? LwsV : LhsV)[rem] = v;
        }
    }
    __syncthreads();

    // Per-thread T registers: Tr[o2][c] = T[o0+o2, c, h0+hh, w0+4*ww4 .. +3]
    float4 Tr[OPB][CIN];
    {
        const float4* __restrict__ Lh4 = (const float4*)Lhs;
        const float4* __restrict__ Lw4 = (const float4*)Lws;
#pragma unroll
        for (int o2 = 0; o2 < OPB; ++o2)
#pragma unroll
            for (int c = 0; c < CIN; ++c) {
                float4 lh  = Lh4[(o2 * CIN + c) * 32 + hh];
                float4 wv0 = Lw4[(o2 * CIN + c) * 32 + 4 * ww4 + 0];
                float4 wv1 = Lw4[(o2 * CIN + c) * 32 + 4 * ww4 + 1];
                float4 wv2 = Lw4[(o2 * CIN + c) * 32 + 4 * ww4 + 2];
                float4 wv3 = Lw4[(o2 * CIN + c) * 32 + 4 * ww4 + 3];
                Tr[o2][c].x = lh.x * wv0.x + lh.y * wv0.y + lh.z * wv0.z + lh.w * wv0.w;
                Tr[o2][c].y = lh.x * wv1.x + lh.y * wv1.y + lh.z * wv1.z + lh.w * wv1.w;
                Tr[o2][c].z = lh.x * wv2.x + lh.y * wv2.y + lh.z * wv2.z + lh.w * wv2.w;
                Tr[o2][c].w = lh.x * wv3.x + lh.y * wv3.y + lh.z * wv3.z + lh.w * wv3.w;
            }
    }

    const float4* __restrict__ X4 = (const float4*)X;
    f32x4* __restrict__ out4      = (f32x4*)out;
    const float* __restrict__ rs  = sums;
    const float* __restrict__ cs  = sums + SUMS_ELEMS;
    const float b0 = bias[o0];
    const float b1 = bias[o0 + 1];

    const int hg  = h0 + hh;
    const int wgb = w0 + 4 * ww4;
    const size_t xoff = (size_t)hg * (DIMS / 4) + (w0 >> 2) + ww4;  // float4 units in one (n,c) plane

    for (int n = 0; n < NB; ++n) {
        float4 p0 = {0.f, 0.f, 0.f, 0.f};
        float4 p1 = {0.f, 0.f, 0.f, 0.f};
#pragma unroll
        for (int c = 0; c < CIN; ++c) {
            float4 xv = X4[(size_t)(n * CIN + c) * (DIMS * DIMS / 4) + xoff];
            p0.x += xv.x * Tr[0][c].x;
            p0.y += xv.y * Tr[0][c].y;
            p0.z += xv.z * Tr[0][c].z;
            p0.w += xv.w * Tr[0][c].w;
            p1.x += xv.x * Tr[1][c].x;
            p1.y += xv.y * Tr[1][c].y;
            p1.z += xv.z * Tr[1][c].z;
            p1.w += xv.w * Tr[1][c].w;
        }
        // o2 = 0
        {
            float  rv = rs[(n * COUT + o0) * DIMS + hg] + b0;
            float4 cv = *(const float4*)&cs[(n * COUT + o0) * DIMS + wgb];
            f32x4 ov;
            ov.x = rv + cv.x - p0.x;
            ov.y = rv + cv.y - p0.y;
            ov.z = rv + cv.z - p0.z;
            ov.w = rv + cv.w - p0.w;
            if (hg == wgb)     ov.x = 0.f;
            if (hg == wgb + 1) ov.y = 0.f;
            if (hg == wgb + 2) ov.z = 0.f;
            if (hg == wgb + 3) ov.w = 0.f;
            __builtin_nontemporal_store(ov,
                &out4[((size_t)(n * COUT + o0) * DIMS + hg) * (DIMS / 4) + (w0 >> 2) + ww4]);
        }
        // o2 = 1
        {
            float  rv = rs[(n * COUT + o0 + 1) * DIMS + hg] + b1;
            float4 cv = *(const float4*)&cs[(n * COUT + o0 + 1) * DIMS + wgb];
            f32x4 ov;
            ov.x = rv + cv.x - p1.x;
            ov.y = rv + cv.y - p1.y;
            ov.z = rv + cv.z - p1.z;
            ov.w = rv + cv.w - p1.w;
            if (hg == wgb)     ov.x = 0.f;
            if (hg == wgb + 1) ov.y = 0.f;
            if (hg == wgb + 2) ov.z = 0.f;
            if (hg == wgb + 3) ov.w = 0.f;
            __builtin_nontemporal_store(ov,
                &out4[((size_t)(n * COUT + o0 + 1) * DIMS + hg) * (DIMS / 4) + (w0 >> 2) + ww4]);
        }
    }
}

// ---------------------------------------------------------------------------
extern "C" void kernel_launch(void* const* d_in, const int* in_sizes, int n_in,
                              void* d_out, int out_size, void* d_ws, size_t ws_size,
                              hipStream_t stream) {
    (void)in_sizes; (void)n_in; (void)out_size; (void)ws_size;
    const float* X    = (const float*)d_in[0];
    const float* L    = (const float*)d_in[1];
    const float* bias = (const float*)d_in[2];
    float* out = (float*)d_out;
    float* ws  = (float*)d_ws;

    float* Lpk  = ws;                 // 524288 floats
    float* sums = ws + LPK_ELEMS;     // 2 * 262144 floats

    pack_L<<<LPK_ELEMS / 256, 256, 0, stream>>>(L, Lpk);
    sums_kernel<<<dim3(256, 2), 512, 0, stream>>>(X, Lpk, sums);
    final_kernel<<<dim3(COUT / OPB, 256), 256, 0, stream>>>(X, L, bias, sums, out);
}